// Round 23
// baseline (293.292 us; speedup 1.0000x reference)
//
#include <hip/hip_runtime.h>
#include <hip/hip_bf16.h>

typedef __attribute__((ext_vector_type(8))) short   short8v;
typedef __attribute__((ext_vector_type(4))) short   short4v;
typedef __attribute__((ext_vector_type(8))) __bf16  bf16x8;
typedef __attribute__((ext_vector_type(4))) __bf16  bf16x4;
typedef __attribute__((ext_vector_type(4))) float   f32x4;

constexpr int Nn = 2048;

#define GLOAD_LDS(src, dst) \
  __builtin_amdgcn_global_load_lds((__attribute__((address_space(1))) unsigned int*)(src), \
                                   (__attribute__((address_space(3))) unsigned int*)(dst), 16, 0, 0)

#if __has_builtin(__builtin_amdgcn_exp2f)
#define EXP2F(x) __builtin_amdgcn_exp2f(x)
#else
#define EXP2F(x) exp2f(x)
#endif

#if __has_builtin(__builtin_amdgcn_mfma_f32_16x16x16bf16_1k)
#define HAVE_MFMA16 1
#define MFMA16(a, b, c) __builtin_amdgcn_mfma_f32_16x16x16bf16_1k(a, b, c, 0, 0, 0)
#else
#define HAVE_MFMA16 0
#endif

__device__ __forceinline__ unsigned pack_bf16(float lo, float hi) {
  union { __bf16 h[2]; unsigned u; } t;
  t.h[0] = (__bf16)lo; t.h[1] = (__bf16)hi;
  return t.u;
}

// =====================================================================
// MFMA GEMM, tile 128x128, BK=32, 2 WAVES (128 thr), 64x128 per wave.
// Per-wave per K-tile: 12 ds_read_b128 / 32 MFMA (vs 8/16 at 2x2-wave)
// -> 25% less LDS read traffic per FLOP (LDS pipe is the CU-level
// bottleneck: reads+staging ~2300cy vs ~310cy MFMA at 16 waves/CU).
// DOUBLE-buffered 32KB LDS, r9/r20-proven sync: stage(t+1) -> vmcnt(8)
// [8 gload_lds/thread/tile] -> barrier -> compute(t) -> barrier.
// LDS GRANULE SWIZZLE (rule #21): linear LDS dest + pre-swizzled global
// source granule + matching read XOR (lg ^ ((lr>>1)&3)).
// AMODE 0: dense A.  AMODE 1: concat A|A2 at K1 (same lda).
// BMODE 0: dense BT. BMODE 1: concat BT(ldb)|BT2(ldb2) at K1.
// EPI 1: bf16 +bias | 2: fp32 +bias + BF16 resid from Vt ptr (pitch ldc)
// EPI 3: bf16 plain | 4: qkv split with FUSED ROPE on Q|K (enc0/enc1
//        passed in resid0/resid1; Q prescaled by SCQ); V -> Vt scatter.
// =====================================================================
template<int AMODE, int BMODE, int EPI>
__global__ __launch_bounds__(128, 2)
void gemm_mfma(const __bf16* __restrict__ A, const __bf16* __restrict__ A2,
               const __bf16* __restrict__ BT, const __bf16* __restrict__ BT2,
               const float* __restrict__ bias,
               const float* __restrict__ resid0, const float* __restrict__ resid1,
               float* __restrict__ Cf, __bf16* __restrict__ Cb, __bf16* __restrict__ Vt,
               int lda, int ldb, int ldb2, int ldc, int K1, int K)
{
  __shared__ __align__(16) __bf16 As[2][4096];
  __shared__ __align__(16) __bf16 Bs[2][4096];
  const int tid = threadIdx.x;
  const int w = tid >> 6, l = tid & 63;            // 2 waves
  const int lr = l & 15, lg = l >> 4;
  const int row0 = blockIdx.x * 128, col0 = blockIdx.y * 128;

  f32x4 acc[4][8];
#pragma unroll
  for (int i = 0; i < 4; ++i)
#pragma unroll
    for (int j = 0; j < 8; ++j) acc[i][j] = (f32x4){0.f, 0.f, 0.f, 0.f};

  const int srow = l >> 2;                              // local row 0..15
  const int skk  = (((l & 3) ^ ((l >> 3) & 3))) * 8;    // swizzled src granule

  auto stage = [&](int k0, int b) {
#pragma unroll
    for (int s = w; s < 8; s += 2) {
      const int m = s * 16 + srow;
      const __bf16* src;
      if constexpr (AMODE == 0) {
        src = A + (size_t)(row0 + m) * lda + k0 + skk;
      } else {
        const int gk = k0 + skk;
        src = (gk < K1) ? A  + (size_t)(row0 + m) * lda + gk
                        : A2 + (size_t)(row0 + m) * lda + (gk - K1);
      }
      GLOAD_LDS(src, &As[b][s * 512]);
    }
#pragma unroll
    for (int s = w; s < 8; s += 2) {
      const int n = s * 16 + srow;
      const __bf16* src;
      if constexpr (BMODE == 0) {
        src = BT + (size_t)(col0 + n) * ldb + k0 + skk;
      } else {
        const int gk = k0 + skk;
        src = (gk < K1) ? BT  + (size_t)(col0 + n) * ldb + gk
                        : BT2 + (size_t)(col0 + n) * ldb2 + (gk - K1);
      }
      GLOAD_LDS(src, &Bs[b][s * 512]);
    }
  };

  const int nt = K >> 5;
  stage(0, 0);

  const int rsl = (lr >> 1) & 3;                     // read swizzle key

  for (int t = 0; t < nt; ++t) {
    const int p = t & 1;
    if (t + 1 < nt) {
      stage((t + 1) * 32, 1 - p);
      asm volatile("s_waitcnt vmcnt(8)" ::: "memory");   // tile t landed
    } else {
      asm volatile("s_waitcnt vmcnt(0)" ::: "memory");
    }
    __builtin_amdgcn_sched_barrier(0);
    __builtin_amdgcn_s_barrier();
    __builtin_amdgcn_sched_barrier(0);
    bf16x8 af[4], bfv[8];
#pragma unroll
    for (int mi = 0; mi < 4; ++mi)
      af[mi] = *(const bf16x8*)&As[p][(w * 64 + mi * 16 + lr) * 32 + (lg ^ rsl) * 8];
#pragma unroll
    for (int ni = 0; ni < 8; ++ni)
      bfv[ni] = *(const bf16x8*)&Bs[p][(ni * 16 + lr) * 32 + (lg ^ rsl) * 8];
    __builtin_amdgcn_s_setprio(1);
#pragma unroll
    for (int mi = 0; mi < 4; ++mi)
#pragma unroll
      for (int ni = 0; ni < 8; ++ni)
        acc[mi][ni] = __builtin_amdgcn_mfma_f32_16x16x32_bf16(af[mi], bfv[ni], acc[mi][ni], 0, 0, 0);
    __builtin_amdgcn_s_setprio(0);
    __builtin_amdgcn_s_barrier();
  }

  if constexpr (EPI == 4) {
    if (col0 >= 1024) {                       // V path -> Vt[bh][d][n]
      const int b2 = row0 >> 11;
#pragma unroll
      for (int mi = 0; mi < 4; ++mi)
#pragma unroll
        for (int ni = 0; ni < 8; ++ni) {
          const int col = col0 + ni * 16 + lr;
          const int sec = col - 1024, h = sec >> 6, d = sec & 63;
          const int n0 = (row0 + w * 64 + mi * 16 + lg * 4) & 2047;
          union { __bf16 h4[4]; short4 s4; } u;
#pragma unroll
          for (int r = 0; r < 4; ++r) u.h4[r] = (__bf16)(acc[mi][ni][r] + bias[col]);
          *(short4*)&Vt[(size_t)(b2 * 8 + h) * 131072 + (size_t)d * 2048 + n0] = u.s4;
        }
    } else {                                  // Q|K path: fused RoPE
      constexpr float SCQ = 0.125f * 1.44269504089f;
      const float* e = (row0 < 8192) ? resid0 : resid1;   // enc0 / enc1
#pragma unroll
      for (int mi = 0; mi < 4; ++mi)
#pragma unroll
        for (int ni = 0; ni < 8; ++ni) {
          const int col = col0 + ni * 16 + lr;
          const int d = col & 63;
          const float sgn = (col & 1) ? 1.f : -1.f;
          const float scq = (col < 512) ? SCQ : 1.f;
#pragma unroll
          for (int r = 0; r < 4; ++r) {
            const int row = row0 + w * 64 + mi * 16 + lg * 4 + r;
            const long bn = row & 8191;
            const float f0 = e[bn * 64 + d];
            const float f1 = e[524288 + bn * 64 + d];
            const float vb = acc[mi][ni][r] + bias[col];
            const float pb = __shfl_xor(vb, 1, 64);      // paired d value
            Cb[(size_t)row * 1024 + col] = (__bf16)((vb * f0 + sgn * pb * f1) * scq);
          }
        }
    }
    return;
  }

#pragma unroll
  for (int mi = 0; mi < 4; ++mi)
#pragma unroll
    for (int ni = 0; ni < 8; ++ni) {
      const int col = col0 + ni * 16 + lr;
#pragma unroll
      for (int r = 0; r < 4; ++r) {
        const int row = row0 + w * 64 + mi * 16 + lg * 4 + r;
        const float v = acc[mi][ni][r];
        if constexpr (EPI == 1) {
          Cb[(size_t)row * ldc + col] = (__bf16)(v + bias[col]);
        } else if constexpr (EPI == 3) {
          Cb[(size_t)row * ldc + col] = (__bf16)v;
        } else {   // EPI 2: fp32 out, bf16 residual from Vt (pitch ldc)
          const float rv = (float)Vt[(size_t)row * ldc + col];
          Cf[(size_t)row * ldc + col] = v + bias[col] + rv;
        }
      }
    }
}

// =====================================================================
// Flash attention, KVBLK=64, FIXED-MAX softmax, 64 q-rows/wave (nf=4).
// Grid 512, XCD-swizzled. Triple-buffered single-barrier pipeline;
// P packed == 16x16x16 PV B-fragment (zero shfl). Softmax and PV are
// interleaved per-ks (exp2 VALU of step ks+1 can overlap PV MFMA of ks).
// launch_bounds min-waves stays 2 (r5 spill). NOTE r16: T15 dual-sacc
// overlap spills (live state > VGPR budget at nf=4) — do not re-add.
// =====================================================================
__global__ __launch_bounds__(256, 2)
void fa_k(const __bf16* __restrict__ QK, const __bf16* __restrict__ Vg,
          __bf16* __restrict__ Ob)
{
  constexpr float FIXM = 8.f;                    // fixed softmax max (exp2 dom)
  __shared__ __align__(16) __bf16 Ks[3][4096];   // [64 kv][64 d] swizzled
  __shared__ __align__(16) __bf16 Vs[3][4096];   // [64 d][64 kv] swizzled
  const int tid = threadIdx.x;
  const int w = tid >> 6, l = tid & 63;
  const int lr = l & 15, lg = l >> 4;
  const int bid = blockIdx.x;
  const int qi = (bid >> 3) & 7;
  const int bh = (bid & 7) * 8 + (bid >> 6);
  const int b2 = bh >> 3, h = bh & 7;
  const __bf16* Qp = QK + (size_t)b2 * 2048 * 1024 + h * 64;
  const __bf16* Kp = Qp + 512;
  const __bf16* Vp = Vg + (size_t)bh * 131072;
  const int q0 = qi * 256 + w * 64;

  bf16x8 qf[4][2];
#pragma unroll
  for (int nf = 0; nf < 4; ++nf)
#pragma unroll
    for (int kk = 0; kk < 2; ++kk)
      qf[nf][kk] = *(const bf16x8*)&Qp[(size_t)(q0 + nf * 16 + lr) * 1024 + kk * 32 + lg * 8];

  f32x4 oacc[4][4];
#pragma unroll
  for (int i = 0; i < 4; ++i)
#pragma unroll
    for (int j = 0; j < 4; ++j) oacc[i][j] = (f32x4){0.f, 0.f, 0.f, 0.f};
  float rs[4] = {0.f, 0.f, 0.f, 0.f};

#if !HAVE_MFMA16
  const int Sa = (lg & 1) * 32 + lr, Sb2x = Sa + 16;
  const bool hi = (lg >> 1) & 1;
#endif

  auto stage = [&](int kv0, int b) {
#pragma unroll
    for (int i = 0; i < 2; ++i) {
      const int s = w + 4 * i;                       // 0..7
      const int g = s * 64 + l, r = g >> 3, c = g & 7;
      GLOAD_LDS(Kp + (size_t)(kv0 + r) * 1024 + ((c ^ (r & 7)) * 8), &Ks[b][s * 512]);
      GLOAD_LDS(Vp + (size_t)r * 2048 + kv0 + ((c ^ (r & 7)) * 8), &Vs[b][s * 512]);
    }
  };

  stage(0, 0);
  stage(64, 1);
  asm volatile("s_waitcnt vmcnt(4)" ::: "memory");   // own tile-0 loads landed
  __builtin_amdgcn_sched_barrier(0);

  for (int t = 0; t < 32; ++t) {
    const int p = t % 3;
    __builtin_amdgcn_s_barrier();                    // publish tile t
    __builtin_amdgcn_sched_barrier(0);
    if (t + 2 < 32) stage((t + 2) * 64, (t + 2) % 3);

    // ---- S^T[64 kv][64 q] = K @ Q^T (Q pre-scaled) ----
    f32x4 sacc[4][4];
#pragma unroll
    for (int i = 0; i < 4; ++i)
#pragma unroll
      for (int j = 0; j < 4; ++j) sacc[i][j] = (f32x4){0.f, 0.f, 0.f, 0.f};
#pragma unroll
    for (int kk = 0; kk < 2; ++kk) {
      bf16x8 ka[4];
#pragma unroll
      for (int mf = 0; mf < 4; ++mf)
        ka[mf] = *(const bf16x8*)&Ks[p][(mf * 16 + lr) * 64 + (((kk * 4 + lg) ^ (lr & 7)) * 8)];
      __builtin_amdgcn_s_setprio(1);
#pragma unroll
      for (int mf = 0; mf < 4; ++mf)
#pragma unroll
        for (int nf = 0; nf < 4; ++nf)
          sacc[mf][nf] = __builtin_amdgcn_mfma_f32_16x16x32_bf16(ka[mf], qf[nf][kk], sacc[mf][nf], 0, 0, 0);
      __builtin_amdgcn_s_setprio(0);
    }

#if HAVE_MFMA16
    // ---- interleaved: softmax(ks) -> PV(ks), ks = 0..3 ----
#pragma unroll
    for (int ks = 0; ks < 4; ++ks) {
      unsigned pkk[4][2];
#pragma unroll
      for (int nf = 0; nf < 4; ++nf) {
        const float p0 = EXP2F(sacc[ks][nf][0] - FIXM);
        const float p1 = EXP2F(sacc[ks][nf][1] - FIXM);
        const float p2 = EXP2F(sacc[ks][nf][2] - FIXM);
        const float p3 = EXP2F(sacc[ks][nf][3] - FIXM);
        rs[nf] += (p0 + p1) + (p2 + p3);
        pkk[nf][0] = pack_bf16(p0, p1);
        pkk[nf][1] = pack_bf16(p2, p3);
      }
      bf16x4 va[4];
#pragma unroll
      for (int mo = 0; mo < 4; ++mo) {
        const int g = (ks * 2 + (lg >> 1)) ^ (lr & 7);
        va[mo] = *(const bf16x4*)&Vs[p][(mo * 16 + lr) * 64 + g * 8 + (lg & 1) * 4];
      }
      __builtin_amdgcn_s_setprio(1);
#pragma unroll
      for (int mo = 0; mo < 4; ++mo)
#pragma unroll
        for (int nf = 0; nf < 4; ++nf)
          oacc[mo][nf] = MFMA16(__builtin_bit_cast(short4v, va[mo]),
                                __builtin_bit_cast(short4v, pkk[nf]),
                                oacc[mo][nf]);
      __builtin_amdgcn_s_setprio(0);
    }
#else
    // ---- fallback: full softmax then 16x16x32 PV with shfl ----
    unsigned pkkf[4][4][2];
#pragma unroll
    for (int nf = 0; nf < 4; ++nf) {
#pragma unroll
      for (int mf = 0; mf < 4; ++mf) {
        const float p0 = EXP2F(sacc[mf][nf][0] - FIXM);
        const float p1 = EXP2F(sacc[mf][nf][1] - FIXM);
        const float p2 = EXP2F(sacc[mf][nf][2] - FIXM);
        const float p3 = EXP2F(sacc[mf][nf][3] - FIXM);
        rs[nf] += (p0 + p1) + (p2 + p3);
        pkkf[mf][nf][0] = pack_bf16(p0, p1);
        pkkf[mf][nf][1] = pack_bf16(p2, p3);
      }
    }
#pragma unroll
    for (int kf = 0; kf < 2; ++kf) {
      bf16x8 va[4];
#pragma unroll
      for (int mo = 0; mo < 4; ++mo) {
        const int g = ((kf * 4 + lg) ^ (lr & 7));
        va[mo] = *(const bf16x8*)&Vs[p][(mo * 16 + lr) * 64 + g * 8];
      }
      bf16x8 bfr[4];
#pragma unroll
      for (int nf = 0; nf < 4; ++nf) {
        const unsigned s0 = hi ? pkkf[kf * 2 + 1][nf][0] : pkkf[kf * 2][nf][0];
        const unsigned s1 = hi ? pkkf[kf * 2 + 1][nf][1] : pkkf[kf * 2][nf][1];
        union { unsigned u[4]; bf16x8 v; } ub;
        ub.u[0] = (unsigned)__shfl((int)s0, Sa, 64);
        ub.u[1] = (unsigned)__shfl((int)s1, Sa, 64);
        ub.u[2] = (unsigned)__shfl((int)s0, Sb2x, 64);
        ub.u[3] = (unsigned)__shfl((int)s1, Sb2x, 64);
        bfr[nf] = ub.v;
      }
      __builtin_amdgcn_s_setprio(1);
#pragma unroll
      for (int mo = 0; mo < 4; ++mo)
#pragma unroll
        for (int nf = 0; nf < 4; ++nf)
          oacc[mo][nf] = __builtin_amdgcn_mfma_f32_16x16x32_bf16(va[mo], bfr[nf], oacc[mo][nf], 0, 0, 0);
      __builtin_amdgcn_s_setprio(0);
    }
#endif
    if (t < 31) {
      if (t + 2 < 32) asm volatile("s_waitcnt vmcnt(4)" ::: "memory");
      else            asm volatile("s_waitcnt vmcnt(0)" ::: "memory");
    }
    __builtin_amdgcn_sched_barrier(0);
  }

  // ---- epilogue: single cross-lane denominator reduce, then store ----
#pragma unroll
  for (int nf = 0; nf < 4; ++nf) {
    float ls = rs[nf];
    ls += __shfl_xor(ls, 16, 64);
    ls += __shfl_xor(ls, 32, 64);
    const float inv = 1.f / ls;
    const long row = (long)b2 * 2048 + q0 + nf * 16 + lr;
#pragma unroll
    for (int mo = 0; mo < 4; ++mo) {
      union { __bf16 h4[4]; short4 s4; } u;
#pragma unroll
      for (int r = 0; r < 4; ++r) u.h4[r] = (__bf16)(oacc[mo][nf][r] * inv);
      *(short4*)&Ob[row * 512 + h * 64 + mo * 16 + lg * 4] = u.s4;
    }
  }
}

// =====================================================================
// prep_all: ALL independent prep in one launch.
// grid 10762: [0,8192) x0|x1 -> xb bf16 | [8192,10496) weight transposes |
// [10496,10752) Wproj conv | [10752,10758) bperm | [10758,10762) bfuse
// =====================================================================
__global__ __launch_bounds__(256)
void prep_all_k(const float* __restrict__ x0, const float* __restrict__ x1,
                const float* __restrict__ Wqkv, const float* __restrict__ W1,
                const float* __restrict__ W2, const float* __restrict__ Wproj,
                const float* __restrict__ bqkv, const float* __restrict__ b1,
                const float* __restrict__ bproj,
                __bf16* __restrict__ xb, __bf16* __restrict__ WqkvT,
                __bf16* __restrict__ W1T, __bf16* __restrict__ W2T,
                __bf16* __restrict__ Wproj_b, float* __restrict__ bqkvp,
                float* __restrict__ b1f)
{
  const int bid = blockIdx.x, tid = threadIdx.x;
  if (bid < 8192) {                                   // x0|x1 -> xb bf16
    const float* s = (bid < 4096) ? x0 : x1;
    __bf16* dd = xb + ((bid < 4096) ? 0 : 4194304);
    const long i = ((long)(bid & 4095) * 256 + tid) * 4;
    const float4 v = *(const float4*)&s[i];
    union { __bf16 h[4]; short4 sv; } u;
    u.h[0] = (__bf16)v.x; u.h[1] = (__bf16)v.y; u.h[2] = (__bf16)v.z; u.h[3] = (__bf16)v.w;
    *(short4*)&dd[i] = u.sv;
  } else if (bid < 10496) {                           // weight transposes
    const int b = bid - 8192;
    const float* W; __bf16* WT; int K, N, bx, by; bool perm = false;
    if (b < 768)       { W = Wqkv; WT = WqkvT; K = 512;  N = 1536; bx = b % 48;          by = b / 48;          perm = true; }
    else if (b < 1792) { W = W1;   WT = W1T;   K = 1024; N = 1024; bx = (b - 768) % 32;  by = (b - 768) / 32; }
    else               { W = W2;   WT = W2T;   K = 1024; N = 512;  bx = (b - 1792) % 16; by = (b - 1792) / 16; }
    __shared__ float t[32][33];
    const int n0 = bx * 32, k0 = by * 32;
    const int tx = tid & 31, ty = tid >> 5;
    for (int i = ty; i < 32; i += 8)
      t[i][tx] = W[(size_t)(k0 + i) * N + n0 + tx];
    __syncthreads();
    for (int i = ty; i < 32; i += 8) {
      int drow = n0 + i;
      if (perm) {
        const int hh = drow / 192, rem = drow % 192;
        drow = (rem % 3) * 512 + hh * 64 + rem / 3;
      }
      WT[(size_t)drow * K + k0 + tx] = (__bf16)t[tx][i];
    }
  } else if (bid < 10752) {                           // Wproj fp32->bf16
    const long i = ((long)(bid - 10496) * 256 + tid) * 4;
    const float4 v = *(const float4*)&Wproj[i];
    union { __bf16 h[4]; short4 sv; } u;
    u.h[0] = (__bf16)v.x; u.h[1] = (__bf16)v.y; u.h[2] = (__bf16)v.z; u.h[3] = (__bf16)v.w;
    *(short4*)&Wproj_b[i] = u.sv;
  } else if (bid < 10758) {                           // bperm
    const int i = (bid - 10752) * 256 + tid;
    if (i < 1536) {
      const int hh = i / 192, rem = i % 192;
      bqkvp[(rem % 3) * 512 + hh * 64 + rem / 3] = bqkv[i];
    }
  } else {                                            // bfuse
    const int n = (bid - 10758) * 256 + tid;
    float s = b1[n];
    for (int m = 0; m < 512; ++m)
      s += bproj[m] * W1[(size_t)(512 + m) * 1024 + n];
    b1f[n] = s;
  }
}

// ---------------- LayerNorm + exact GELU, in-place bf16 [.][1024] ------
// 256 thr/row, 4 elems/thread; wave shfl reduce + 1 LDS stage (1 barrier).
__global__ __launch_bounds__(256)
void ln_gelu_k(__bf16* __restrict__ Hb, const float* __restrict__ g,
               const float* __restrict__ be)
{
  __bf16* row = Hb + (size_t)blockIdx.x * 1024;
  const int tid = threadIdx.x, w = tid >> 6, l = tid & 63;
  __shared__ float ps[4][2];
  union { __bf16 h[4]; short4 sv; } u;
  u.sv = *(const short4*)&row[tid * 4];
  float v[4];
  float s = 0.f, sq = 0.f;
#pragma unroll
  for (int i = 0; i < 4; ++i) {
    v[i] = (float)u.h[i];
    s += v[i]; sq += v[i] * v[i];
  }
#pragma unroll
  for (int d = 32; d > 0; d >>= 1) {
    s  += __shfl_xor(s, d, 64);
    sq += __shfl_xor(sq, d, 64);
  }
  if (l == 0) { ps[w][0] = s; ps[w][1] = sq; }
  __syncthreads();
  s  = ps[0][0] + ps[1][0] + ps[2][0] + ps[3][0];
  sq = ps[0][1] + ps[1][1] + ps[2][1] + ps[3][1];
  const float mu = s * (1.f / 1024.f);
  const float var = sq * (1.f / 1024.f) - mu * mu;
  const float rstd = rsqrtf(var + 1e-5f);
#pragma unroll
  for (int i = 0; i < 4; ++i) {
    const int c = tid * 4 + i;
    const float y = (v[i] - mu) * rstd * g[c] + be[c];
    u.h[i] = (__bf16)(0.5f * y * (1.f + erff(y * 0.70710678118f)));
  }
  *(short4*)&row[tid * 4] = u.sv;
}

extern "C" void kernel_launch(void* const* d_in, const int* in_sizes, int n_in,
                              void* d_out, int out_size, void* d_ws, size_t ws_size,
                              hipStream_t stream)
{
  const float* x0   = (const float*)d_in[0];
  const float* x1   = (const float*)d_in[1];
  const float* enc0 = (const float*)d_in[2];
  const float* enc1 = (const float*)d_in[3];
  const float* Wqkv  = (const float*)d_in[4];
  const float* bqkv  = (const float*)d_in[5];
  const float* Wproj = (const float*)d_in[6];
  const float* bproj = (const float*)d_in[7];
  const float* W1    = (const float*)d_in[8];
  const float* b1    = (const float*)d_in[9];
  const float* ln_g  = (const float*)d_in[10];
  const float* ln_b  = (const float*)d_in[11];
  const float* W2    = (const float*)d_in[12];
  const float* b2    = (const float*)d_in[13];

  __bf16* wsb = (__bf16*)d_ws;
  __bf16* xb      = wsb;                    // [16384][512]            8,388,608
  __bf16* WqkvT   = wsb + 8388608;          // [1536][512]               786,432
  __bf16* Wproj_b = wsb + 9175040;          // [512][512] (row-major)    262,144
  __bf16* W1T     = wsb + 9437184;          // [1024][1024]            1,048,576
  __bf16* W2T     = wsb + 10485760;         // [512][1024]               524,288
  float*  bqkvp   = (float*)(wsb + 11010048); // 1536 fp32 (3072 slots)
  __bf16* qkvb    = wsb + 11013120;         // [16384][1024] Q|K      16,777,216
  __bf16* Vt      = wsb + 27790336;         // [64][64][2048]          8,388,608
  __bf16* Ob      = wsb + 36178944;         // [16384][512]            8,388,608
  __bf16* WfT     = wsb + 44567552;         // [1024][512] W'^T          524,288
  float*  b1f     = (float*)(wsb + 45091840); // 1024 fp32 (2048 slots)
  __bf16* hb      = qkvb;                   // alias qkvb (dead after fa_k).
  // NOTE: hb must NOT alias Vt/Ob — step 3 READS Ob while WRITING hb
  // (r8 bug: hb=Vt overlapped Ob -> inter-block race, absmax 0.297).
  // end: 45,093,888 bf16 = 90.2 MB (< 100.7 MB proven in r2)

  // ---- prep: one launch for all independent work ----
  prep_all_k<<<10762, 256, 0, stream>>>(x0, x1, Wqkv, W1, W2, Wproj,
                                        bqkv, b1, bproj,
                                        xb, WqkvT, W1T, W2T, Wproj_b, bqkvp, b1f);
  // W'^T[n][j] = sum_m W1T[n][512+m] * Wproj[j][m]   (proj folded into W1)
  gemm_mfma<0, 0, 3><<<dim3(8, 4), 128, 0, stream>>>(
      W1T + 512, nullptr, Wproj_b, nullptr, nullptr, nullptr, nullptr,
      nullptr, WfT, nullptr, 1024, 512, 0, 512, 0, 512);

  // 1. qkv GEMM with FUSED ROPE: Q|K -> qkvb bf16 (Q prescaled), V -> Vt
  gemm_mfma<0, 0, 4><<<dim3(128, 12), 128, 0, stream>>>(
      xb, nullptr, WqkvT, nullptr, bqkvp, enc0, enc1, nullptr, qkvb, Vt,
      512, 512, 0, 1024, 0, 512);
  // 2. flash attention -> Ob (XCD-swizzled 1D grid, 64 q-rows/wave)
  fa_k<<<512, 256, 0, stream>>>(qkvb, Vt, Ob);
  // 3. h = [x | O] @ [W1_top ; W'] + b1f -> hb bf16 (proj GEMM eliminated)
  gemm_mfma<1, 1, 1><<<dim3(128, 8), 128, 0, stream>>>(
      xb, Ob, W1T, WfT, b1f, nullptr, nullptr, nullptr, hb, nullptr,
      512, 1024, 512, 1024, 512, 1024);
  // 4. LayerNorm + GELU in place
  ln_gelu_k<<<16384, 256, 0, stream>>>(hb, ln_g, ln_b);
  // 5. out = x + g @ W2 + b2 -> fp32 d_out (bf16 resid from xb via Vt slot)
  gemm_mfma<0, 0, 2><<<dim3(128, 4), 128, 0, stream>>>(
      hb, nullptr, W2T, nullptr, b2, nullptr, nullptr, (float*)d_out, nullptr, xb,
      1024, 1024, 0, 512, 0, 1024);
}

// Round 24
// 287.498 us; speedup vs baseline: 1.0202x; 1.0202x over previous
//
#include <hip/hip_runtime.h>
#include <hip/hip_bf16.h>

typedef __attribute__((ext_vector_type(8))) short   short8v;
typedef __attribute__((ext_vector_type(4))) short   short4v;
typedef __attribute__((ext_vector_type(8))) __bf16  bf16x8;
typedef __attribute__((ext_vector_type(4))) __bf16  bf16x4;
typedef __attribute__((ext_vector_type(4))) float   f32x4;

constexpr int Nn = 2048;

#define GLOAD_LDS(src, dst) \
  __builtin_amdgcn_global_load_lds((__attribute__((address_space(1))) unsigned int*)(src), \
                                   (__attribute__((address_space(3))) unsigned int*)(dst), 16, 0, 0)

#if __has_builtin(__builtin_amdgcn_exp2f)
#define EXP2F(x) __builtin_amdgcn_exp2f(x)
#else
#define EXP2F(x) exp2f(x)
#endif

#if __has_builtin(__builtin_amdgcn_mfma_f32_16x16x16bf16_1k)
#define HAVE_MFMA16 1
#define MFMA16(a, b, c) __builtin_amdgcn_mfma_f32_16x16x16bf16_1k(a, b, c, 0, 0, 0)
#else
#define HAVE_MFMA16 0
#endif

__device__ __forceinline__ unsigned pack_bf16(float lo, float hi) {
  union { __bf16 h[2]; unsigned u; } t;
  t.h[0] = (__bf16)lo; t.h[1] = (__bf16)hi;
  return t.u;
}

// =====================================================================
// MFMA GEMM, tile 128x128, BK=32, 4 waves (2x2). B passed as B^T [N][K].
// DOUBLE-buffered 32KB LDS (r9-proven two-barrier sync): stage(t+1) ->
// vmcnt(4) [oldest 4 = tile t landed] -> barrier -> compute(t) -> barrier.
// 32KB -> 4 blocks/CU, 16 waves/CU. CONVERGED GEOMETRY: r18 (128x256,
// 72KB) and r23 (2-wave, VGPR-doubled -> 8 waves/CU) both regressed —
// wave-width gains lose to occupancy. Do not re-widen.
// LDS GRANULE SWIZZLE (rule #21): linear LDS dest + pre-swizzled global
// source granule + matching read XOR (lg ^ ((lr>>1)&3)).
// AMODE 0: dense A.  AMODE 1: concat A|A2 at K1 (same lda).
// BMODE 0: dense BT. BMODE 1: concat BT(ldb)|BT2(ldb2) at K1.
// EPI 1: bf16 +bias | 2: fp32 +bias + BF16 resid from Vt ptr (pitch ldc)
// EPI 3: bf16 plain | 4: qkv split with FUSED ROPE on Q|K (enc0/enc1
//        passed in resid0/resid1; Q prescaled by SCQ); V -> Vt scatter.
// =====================================================================
template<int AMODE, int BMODE, int EPI>
__global__ __launch_bounds__(256)
void gemm_mfma(const __bf16* __restrict__ A, const __bf16* __restrict__ A2,
               const __bf16* __restrict__ BT, const __bf16* __restrict__ BT2,
               const float* __restrict__ bias,
               const float* __restrict__ resid0, const float* __restrict__ resid1,
               float* __restrict__ Cf, __bf16* __restrict__ Cb, __bf16* __restrict__ Vt,
               int lda, int ldb, int ldb2, int ldc, int K1, int K)
{
  __shared__ __align__(16) __bf16 As[2][4096];
  __shared__ __align__(16) __bf16 Bs[2][4096];
  const int tid = threadIdx.x;
  const int w = tid >> 6, l = tid & 63;
  const int wr = w >> 1, wc = w & 1;
  const int lr = l & 15, lg = l >> 4;
  const int row0 = blockIdx.x * 128, col0 = blockIdx.y * 128;

  f32x4 acc[4][4];
#pragma unroll
  for (int i = 0; i < 4; ++i)
#pragma unroll
    for (int j = 0; j < 4; ++j) acc[i][j] = (f32x4){0.f, 0.f, 0.f, 0.f};

  const int srow = l >> 2;                              // local row 0..15
  const int skk  = (((l & 3) ^ ((l >> 3) & 3))) * 8;    // swizzled src granule

  auto stage = [&](int k0, int b) {
#pragma unroll
    for (int s = w; s < 8; s += 4) {
      const int m = s * 16 + srow;
      const __bf16* src;
      if constexpr (AMODE == 0) {
        src = A + (size_t)(row0 + m) * lda + k0 + skk;
      } else {
        const int gk = k0 + skk;
        src = (gk < K1) ? A  + (size_t)(row0 + m) * lda + gk
                        : A2 + (size_t)(row0 + m) * lda + (gk - K1);
      }
      GLOAD_LDS(src, &As[b][s * 512]);
    }
#pragma unroll
    for (int s = w; s < 8; s += 4) {
      const int n = s * 16 + srow;
      const __bf16* src;
      if constexpr (BMODE == 0) {
        src = BT + (size_t)(col0 + n) * ldb + k0 + skk;
      } else {
        const int gk = k0 + skk;
        src = (gk < K1) ? BT  + (size_t)(col0 + n) * ldb + gk
                        : BT2 + (size_t)(col0 + n) * ldb2 + (gk - K1);
      }
      GLOAD_LDS(src, &Bs[b][s * 512]);
    }
  };

  const int nt = K >> 5;
  stage(0, 0);

  const int rsl = (lr >> 1) & 3;                     // read swizzle key

  for (int t = 0; t < nt; ++t) {
    const int p = t & 1;
    if (t + 1 < nt) {
      stage((t + 1) * 32, 1 - p);
      asm volatile("s_waitcnt vmcnt(4)" ::: "memory");   // tile t landed
    } else {
      asm volatile("s_waitcnt vmcnt(0)" ::: "memory");
    }
    __builtin_amdgcn_sched_barrier(0);
    __builtin_amdgcn_s_barrier();
    __builtin_amdgcn_sched_barrier(0);
    bf16x8 af[4], bfv[4];
#pragma unroll
    for (int mi = 0; mi < 4; ++mi)
      af[mi] = *(const bf16x8*)&As[p][(wr * 64 + mi * 16 + lr) * 32 + (lg ^ rsl) * 8];
#pragma unroll
    for (int ni = 0; ni < 4; ++ni)
      bfv[ni] = *(const bf16x8*)&Bs[p][(wc * 64 + ni * 16 + lr) * 32 + (lg ^ rsl) * 8];
    __builtin_amdgcn_s_setprio(1);
#pragma unroll
    for (int mi = 0; mi < 4; ++mi)
#pragma unroll
      for (int ni = 0; ni < 4; ++ni)
        acc[mi][ni] = __builtin_amdgcn_mfma_f32_16x16x32_bf16(af[mi], bfv[ni], acc[mi][ni], 0, 0, 0);
    __builtin_amdgcn_s_setprio(0);
    __builtin_amdgcn_s_barrier();
  }

  if constexpr (EPI == 4) {
    if (col0 >= 1024) {                       // V path -> Vt[bh][d][n]
      const int b2 = row0 >> 11;
#pragma unroll
      for (int mi = 0; mi < 4; ++mi)
#pragma unroll
        for (int ni = 0; ni < 4; ++ni) {
          const int col = col0 + wc * 64 + ni * 16 + lr;
          const int sec = col - 1024, h = sec >> 6, d = sec & 63;
          const int n0 = (row0 + wr * 64 + mi * 16 + lg * 4) & 2047;
          union { __bf16 h4[4]; short4 s4; } u;
#pragma unroll
          for (int r = 0; r < 4; ++r) u.h4[r] = (__bf16)(acc[mi][ni][r] + bias[col]);
          *(short4*)&Vt[(size_t)(b2 * 8 + h) * 131072 + (size_t)d * 2048 + n0] = u.s4;
        }
    } else {                                  // Q|K path: fused RoPE
      constexpr float SCQ = 0.125f * 1.44269504089f;
      const float* e = (row0 < 8192) ? resid0 : resid1;   // enc0 / enc1
#pragma unroll
      for (int mi = 0; mi < 4; ++mi)
#pragma unroll
        for (int ni = 0; ni < 4; ++ni) {
          const int col = col0 + wc * 64 + ni * 16 + lr;
          const int d = col & 63;
          const float sgn = (col & 1) ? 1.f : -1.f;
          const float scq = (col < 512) ? SCQ : 1.f;
#pragma unroll
          for (int r = 0; r < 4; ++r) {
            const int row = row0 + wr * 64 + mi * 16 + lg * 4 + r;
            const long bn = row & 8191;
            const float f0 = e[bn * 64 + d];
            const float f1 = e[524288 + bn * 64 + d];
            const float vb = acc[mi][ni][r] + bias[col];
            const float pb = __shfl_xor(vb, 1, 64);      // paired d value
            Cb[(size_t)row * 1024 + col] = (__bf16)((vb * f0 + sgn * pb * f1) * scq);
          }
        }
    }
    return;
  }

#pragma unroll
  for (int mi = 0; mi < 4; ++mi)
#pragma unroll
    for (int ni = 0; ni < 4; ++ni) {
      const int col = col0 + wc * 64 + ni * 16 + lr;
#pragma unroll
      for (int r = 0; r < 4; ++r) {
        const int row = row0 + wr * 64 + mi * 16 + lg * 4 + r;
        const float v = acc[mi][ni][r];
        if constexpr (EPI == 1) {
          Cb[(size_t)row * ldc + col] = (__bf16)(v + bias[col]);
        } else if constexpr (EPI == 3) {
          Cb[(size_t)row * ldc + col] = (__bf16)v;
        } else {   // EPI 2: fp32 out, bf16 residual from Vt (pitch ldc)
          const float rv = (float)Vt[(size_t)row * ldc + col];
          Cf[(size_t)row * ldc + col] = v + bias[col] + rv;
        }
      }
    }
}

// =====================================================================
// Flash attention, KVBLK=64, FIXED-MAX softmax, 64 q-rows/wave (nf=4).
// Grid 512, XCD-swizzled. Triple-buffered single-barrier pipeline;
// P packed == 16x16x16 PV B-fragment (zero shfl). Softmax and PV are
// interleaved per-ks (exp2 VALU of step ks+1 can overlap PV MFMA of ks).
// launch_bounds min-waves stays 2 (r5 spill). NOTE r16: T15 dual-sacc
// overlap spills (live state > VGPR budget at nf=4) — do not re-add.
// =====================================================================
__global__ __launch_bounds__(256, 2)
void fa_k(const __bf16* __restrict__ QK, const __bf16* __restrict__ Vg,
          __bf16* __restrict__ Ob)
{
  constexpr float FIXM = 8.f;                    // fixed softmax max (exp2 dom)
  __shared__ __align__(16) __bf16 Ks[3][4096];   // [64 kv][64 d] swizzled
  __shared__ __align__(16) __bf16 Vs[3][4096];   // [64 d][64 kv] swizzled
  const int tid = threadIdx.x;
  const int w = tid >> 6, l = tid & 63;
  const int lr = l & 15, lg = l >> 4;
  const int bid = blockIdx.x;
  const int qi = (bid >> 3) & 7;
  const int bh = (bid & 7) * 8 + (bid >> 6);
  const int b2 = bh >> 3, h = bh & 7;
  const __bf16* Qp = QK + (size_t)b2 * 2048 * 1024 + h * 64;
  const __bf16* Kp = Qp + 512;
  const __bf16* Vp = Vg + (size_t)bh * 131072;
  const int q0 = qi * 256 + w * 64;

  bf16x8 qf[4][2];
#pragma unroll
  for (int nf = 0; nf < 4; ++nf)
#pragma unroll
    for (int kk = 0; kk < 2; ++kk)
      qf[nf][kk] = *(const bf16x8*)&Qp[(size_t)(q0 + nf * 16 + lr) * 1024 + kk * 32 + lg * 8];

  f32x4 oacc[4][4];
#pragma unroll
  for (int i = 0; i < 4; ++i)
#pragma unroll
    for (int j = 0; j < 4; ++j) oacc[i][j] = (f32x4){0.f, 0.f, 0.f, 0.f};
  float rs[4] = {0.f, 0.f, 0.f, 0.f};

#if !HAVE_MFMA16
  const int Sa = (lg & 1) * 32 + lr, Sb2x = Sa + 16;
  const bool hi = (lg >> 1) & 1;
#endif

  auto stage = [&](int kv0, int b) {
#pragma unroll
    for (int i = 0; i < 2; ++i) {
      const int s = w + 4 * i;                       // 0..7
      const int g = s * 64 + l, r = g >> 3, c = g & 7;
      GLOAD_LDS(Kp + (size_t)(kv0 + r) * 1024 + ((c ^ (r & 7)) * 8), &Ks[b][s * 512]);
      GLOAD_LDS(Vp + (size_t)r * 2048 + kv0 + ((c ^ (r & 7)) * 8), &Vs[b][s * 512]);
    }
  };

  stage(0, 0);
  stage(64, 1);
  asm volatile("s_waitcnt vmcnt(4)" ::: "memory");   // own tile-0 loads landed
  __builtin_amdgcn_sched_barrier(0);

  for (int t = 0; t < 32; ++t) {
    const int p = t % 3;
    __builtin_amdgcn_s_barrier();                    // publish tile t
    __builtin_amdgcn_sched_barrier(0);
    if (t + 2 < 32) stage((t + 2) * 64, (t + 2) % 3);

    // ---- S^T[64 kv][64 q] = K @ Q^T (Q pre-scaled) ----
    f32x4 sacc[4][4];
#pragma unroll
    for (int i = 0; i < 4; ++i)
#pragma unroll
      for (int j = 0; j < 4; ++j) sacc[i][j] = (f32x4){0.f, 0.f, 0.f, 0.f};
#pragma unroll
    for (int kk = 0; kk < 2; ++kk) {
      bf16x8 ka[4];
#pragma unroll
      for (int mf = 0; mf < 4; ++mf)
        ka[mf] = *(const bf16x8*)&Ks[p][(mf * 16 + lr) * 64 + (((kk * 4 + lg) ^ (lr & 7)) * 8)];
      __builtin_amdgcn_s_setprio(1);
#pragma unroll
      for (int mf = 0; mf < 4; ++mf)
#pragma unroll
        for (int nf = 0; nf < 4; ++nf)
          sacc[mf][nf] = __builtin_amdgcn_mfma_f32_16x16x32_bf16(ka[mf], qf[nf][kk], sacc[mf][nf], 0, 0, 0);
      __builtin_amdgcn_s_setprio(0);
    }

#if HAVE_MFMA16
    // ---- interleaved: softmax(ks) -> PV(ks), ks = 0..3 ----
#pragma unroll
    for (int ks = 0; ks < 4; ++ks) {
      unsigned pkk[4][2];
#pragma unroll
      for (int nf = 0; nf < 4; ++nf) {
        const float p0 = EXP2F(sacc[ks][nf][0] - FIXM);
        const float p1 = EXP2F(sacc[ks][nf][1] - FIXM);
        const float p2 = EXP2F(sacc[ks][nf][2] - FIXM);
        const float p3 = EXP2F(sacc[ks][nf][3] - FIXM);
        rs[nf] += (p0 + p1) + (p2 + p3);
        pkk[nf][0] = pack_bf16(p0, p1);
        pkk[nf][1] = pack_bf16(p2, p3);
      }
      bf16x4 va[4];
#pragma unroll
      for (int mo = 0; mo < 4; ++mo) {
        const int g = (ks * 2 + (lg >> 1)) ^ (lr & 7);
        va[mo] = *(const bf16x4*)&Vs[p][(mo * 16 + lr) * 64 + g * 8 + (lg & 1) * 4];
      }
      __builtin_amdgcn_s_setprio(1);
#pragma unroll
      for (int mo = 0; mo < 4; ++mo)
#pragma unroll
        for (int nf = 0; nf < 4; ++nf)
          oacc[mo][nf] = MFMA16(__builtin_bit_cast(short4v, va[mo]),
                                __builtin_bit_cast(short4v, pkk[nf]),
                                oacc[mo][nf]);
      __builtin_amdgcn_s_setprio(0);
    }
#else
    // ---- fallback: full softmax then 16x16x32 PV with shfl ----
    unsigned pkkf[4][4][2];
#pragma unroll
    for (int nf = 0; nf < 4; ++nf) {
#pragma unroll
      for (int mf = 0; mf < 4; ++mf) {
        const float p0 = EXP2F(sacc[mf][nf][0] - FIXM);
        const float p1 = EXP2F(sacc[mf][nf][1] - FIXM);
        const float p2 = EXP2F(sacc[mf][nf][2] - FIXM);
        const float p3 = EXP2F(sacc[mf][nf][3] - FIXM);
        rs[nf] += (p0 + p1) + (p2 + p3);
        pkkf[mf][nf][0] = pack_bf16(p0, p1);
        pkkf[mf][nf][1] = pack_bf16(p2, p3);
      }
    }
#pragma unroll
    for (int kf = 0; kf < 2; ++kf) {
      bf16x8 va[4];
#pragma unroll
      for (int mo = 0; mo < 4; ++mo) {
        const int g = ((kf * 4 + lg) ^ (lr & 7));
        va[mo] = *(const bf16x8*)&Vs[p][(mo * 16 + lr) * 64 + g * 8];
      }
      bf16x8 bfr[4];
#pragma unroll
      for (int nf = 0; nf < 4; ++nf) {
        const unsigned s0 = hi ? pkkf[kf * 2 + 1][nf][0] : pkkf[kf * 2][nf][0];
        const unsigned s1 = hi ? pkkf[kf * 2 + 1][nf][1] : pkkf[kf * 2][nf][1];
        union { unsigned u[4]; bf16x8 v; } ub;
        ub.u[0] = (unsigned)__shfl((int)s0, Sa, 64);
        ub.u[1] = (unsigned)__shfl((int)s1, Sa, 64);
        ub.u[2] = (unsigned)__shfl((int)s0, Sb2x, 64);
        ub.u[3] = (unsigned)__shfl((int)s1, Sb2x, 64);
        bfr[nf] = ub.v;
      }
      __builtin_amdgcn_s_setprio(1);
#pragma unroll
      for (int mo = 0; mo < 4; ++mo)
#pragma unroll
        for (int nf = 0; nf < 4; ++nf)
          oacc[mo][nf] = __builtin_amdgcn_mfma_f32_16x16x32_bf16(va[mo], bfr[nf], oacc[mo][nf], 0, 0, 0);
      __builtin_amdgcn_s_setprio(0);
    }
#endif
    if (t < 31) {
      if (t + 2 < 32) asm volatile("s_waitcnt vmcnt(4)" ::: "memory");
      else            asm volatile("s_waitcnt vmcnt(0)" ::: "memory");
    }
    __builtin_amdgcn_sched_barrier(0);
  }

  // ---- epilogue: single cross-lane denominator reduce, then store ----
#pragma unroll
  for (int nf = 0; nf < 4; ++nf) {
    float ls = rs[nf];
    ls += __shfl_xor(ls, 16, 64);
    ls += __shfl_xor(ls, 32, 64);
    const float inv = 1.f / ls;
    const long row = (long)b2 * 2048 + q0 + nf * 16 + lr;
#pragma unroll
    for (int mo = 0; mo < 4; ++mo) {
      union { __bf16 h4[4]; short4 s4; } u;
#pragma unroll
      for (int r = 0; r < 4; ++r) u.h4[r] = (__bf16)(oacc[mo][nf][r] * inv);
      *(short4*)&Ob[row * 512 + h * 64 + mo * 16 + lg * 4] = u.s4;
    }
  }
}

// =====================================================================
// prep_all: ALL independent prep in one launch.
// grid 10762: [0,8192) x0|x1 -> xb bf16 | [8192,10496) weight transposes |
// [10496,10752) Wproj conv | [10752,10758) bperm | [10758,10762) bfuse
// =====================================================================
__global__ __launch_bounds__(256)
void prep_all_k(const float* __restrict__ x0, const float* __restrict__ x1,
                const float* __restrict__ Wqkv, const float* __restrict__ W1,
                const float* __restrict__ W2, const float* __restrict__ Wproj,
                const float* __restrict__ bqkv, const float* __restrict__ b1,
                const float* __restrict__ bproj,
                __bf16* __restrict__ xb, __bf16* __restrict__ WqkvT,
                __bf16* __restrict__ W1T, __bf16* __restrict__ W2T,
                __bf16* __restrict__ Wproj_b, float* __restrict__ bqkvp,
                float* __restrict__ b1f)
{
  const int bid = blockIdx.x, tid = threadIdx.x;
  if (bid < 8192) {                                   // x0|x1 -> xb bf16
    const float* s = (bid < 4096) ? x0 : x1;
    __bf16* dd = xb + ((bid < 4096) ? 0 : 4194304);
    const long i = ((long)(bid & 4095) * 256 + tid) * 4;
    const float4 v = *(const float4*)&s[i];
    union { __bf16 h[4]; short4 sv; } u;
    u.h[0] = (__bf16)v.x; u.h[1] = (__bf16)v.y; u.h[2] = (__bf16)v.z; u.h[3] = (__bf16)v.w;
    *(short4*)&dd[i] = u.sv;
  } else if (bid < 10496) {                           // weight transposes
    const int b = bid - 8192;
    const float* W; __bf16* WT; int K, N, bx, by; bool perm = false;
    if (b < 768)       { W = Wqkv; WT = WqkvT; K = 512;  N = 1536; bx = b % 48;          by = b / 48;          perm = true; }
    else if (b < 1792) { W = W1;   WT = W1T;   K = 1024; N = 1024; bx = (b - 768) % 32;  by = (b - 768) / 32; }
    else               { W = W2;   WT = W2T;   K = 1024; N = 512;  bx = (b - 1792) % 16; by = (b - 1792) / 16; }
    __shared__ float t[32][33];
    const int n0 = bx * 32, k0 = by * 32;
    const int tx = tid & 31, ty = tid >> 5;
    for (int i = ty; i < 32; i += 8)
      t[i][tx] = W[(size_t)(k0 + i) * N + n0 + tx];
    __syncthreads();
    for (int i = ty; i < 32; i += 8) {
      int drow = n0 + i;
      if (perm) {
        const int hh = drow / 192, rem = drow % 192;
        drow = (rem % 3) * 512 + hh * 64 + rem / 3;
      }
      WT[(size_t)drow * K + k0 + tx] = (__bf16)t[tx][i];
    }
  } else if (bid < 10752) {                           // Wproj fp32->bf16
    const long i = ((long)(bid - 10496) * 256 + tid) * 4;
    const float4 v = *(const float4*)&Wproj[i];
    union { __bf16 h[4]; short4 sv; } u;
    u.h[0] = (__bf16)v.x; u.h[1] = (__bf16)v.y; u.h[2] = (__bf16)v.z; u.h[3] = (__bf16)v.w;
    *(short4*)&Wproj_b[i] = u.sv;
  } else if (bid < 10758) {                           // bperm
    const int i = (bid - 10752) * 256 + tid;
    if (i < 1536) {
      const int hh = i / 192, rem = i % 192;
      bqkvp[(rem % 3) * 512 + hh * 64 + rem / 3] = bqkv[i];
    }
  } else {                                            // bfuse
    const int n = (bid - 10758) * 256 + tid;
    float s = b1[n];
    for (int m = 0; m < 512; ++m)
      s += bproj[m] * W1[(size_t)(512 + m) * 1024 + n];
    b1f[n] = s;
  }
}

// ---------------- LayerNorm + exact GELU, in-place bf16 [.][1024] ------
// 256 thr/row, 4 elems/thread; wave shfl reduce + 1 LDS stage (1 barrier).
__global__ __launch_bounds__(256)
void ln_gelu_k(__bf16* __restrict__ Hb, const float* __restrict__ g,
               const float* __restrict__ be)
{
  __bf16* row = Hb + (size_t)blockIdx.x * 1024;
  const int tid = threadIdx.x, w = tid >> 6, l = tid & 63;
  __shared__ float ps[4][2];
  union { __bf16 h[4]; short4 sv; } u;
  u.sv = *(const short4*)&row[tid * 4];
  float v[4];
  float s = 0.f, sq = 0.f;
#pragma unroll
  for (int i = 0; i < 4; ++i) {
    v[i] = (float)u.h[i];
    s += v[i]; sq += v[i] * v[i];
  }
#pragma unroll
  for (int d = 32; d > 0; d >>= 1) {
    s  += __shfl_xor(s, d, 64);
    sq += __shfl_xor(sq, d, 64);
  }
  if (l == 0) { ps[w][0] = s; ps[w][1] = sq; }
  __syncthreads();
  s  = ps[0][0] + ps[1][0] + ps[2][0] + ps[3][0];
  sq = ps[0][1] + ps[1][1] + ps[2][1] + ps[3][1];
  const float mu = s * (1.f / 1024.f);
  const float var = sq * (1.f / 1024.f) - mu * mu;
  const float rstd = rsqrtf(var + 1e-5f);
#pragma unroll
  for (int i = 0; i < 4; ++i) {
    const int c = tid * 4 + i;
    const float y = (v[i] - mu) * rstd * g[c] + be[c];
    u.h[i] = (__bf16)(0.5f * y * (1.f + erff(y * 0.70710678118f)));
  }
  *(short4*)&row[tid * 4] = u.sv;
}

extern "C" void kernel_launch(void* const* d_in, const int* in_sizes, int n_in,
                              void* d_out, int out_size, void* d_ws, size_t ws_size,
                              hipStream_t stream)
{
  const float* x0   = (const float*)d_in[0];
  const float* x1   = (const float*)d_in[1];
  const float* enc0 = (const float*)d_in[2];
  const float* enc1 = (const float*)d_in[3];
  const float* Wqkv  = (const float*)d_in[4];
  const float* bqkv  = (const float*)d_in[5];
  const float* Wproj = (const float*)d_in[6];
  const float* bproj = (const float*)d_in[7];
  const float* W1    = (const float*)d_in[8];
  const float* b1    = (const float*)d_in[9];
  const float* ln_g  = (const float*)d_in[10];
  const float* ln_b  = (const float*)d_in[11];
  const float* W2    = (const float*)d_in[12];
  const float* b2    = (const float*)d_in[13];

  __bf16* wsb = (__bf16*)d_ws;
  __bf16* xb      = wsb;                    // [16384][512]            8,388,608
  __bf16* WqkvT   = wsb + 8388608;          // [1536][512]               786,432
  __bf16* Wproj_b = wsb + 9175040;          // [512][512] (row-major)    262,144
  __bf16* W1T     = wsb + 9437184;          // [1024][1024]            1,048,576
  __bf16* W2T     = wsb + 10485760;         // [512][1024]               524,288
  float*  bqkvp   = (float*)(wsb + 11010048); // 1536 fp32 (3072 slots)
  __bf16* qkvb    = wsb + 11013120;         // [16384][1024] Q|K      16,777,216
  __bf16* Vt      = wsb + 27790336;         // [64][64][2048]          8,388,608
  __bf16* Ob      = wsb + 36178944;         // [16384][512]            8,388,608
  __bf16* WfT     = wsb + 44567552;         // [1024][512] W'^T          524,288
  float*  b1f     = (float*)(wsb + 45091840); // 1024 fp32 (2048 slots)
  __bf16* hb      = qkvb;                   // alias qkvb (dead after fa_k).
  // NOTE: hb must NOT alias Vt/Ob — step 3 READS Ob while WRITING hb
  // (r8 bug: hb=Vt overlapped Ob -> inter-block race, absmax 0.297).
  // end: 45,093,888 bf16 = 90.2 MB (< 100.7 MB proven in r2)

  // ---- prep: one launch for all independent work ----
  prep_all_k<<<10762, 256, 0, stream>>>(x0, x1, Wqkv, W1, W2, Wproj,
                                        bqkv, b1, bproj,
                                        xb, WqkvT, W1T, W2T, Wproj_b, bqkvp, b1f);
  // W'^T[n][j] = sum_m W1T[n][512+m] * Wproj[j][m]   (proj folded into W1)
  gemm_mfma<0, 0, 3><<<dim3(8, 4), 256, 0, stream>>>(
      W1T + 512, nullptr, Wproj_b, nullptr, nullptr, nullptr, nullptr,
      nullptr, WfT, nullptr, 1024, 512, 0, 512, 0, 512);

  // 1. qkv GEMM with FUSED ROPE: Q|K -> qkvb bf16 (Q prescaled), V -> Vt
  gemm_mfma<0, 0, 4><<<dim3(128, 12), 256, 0, stream>>>(
      xb, nullptr, WqkvT, nullptr, bqkvp, enc0, enc1, nullptr, qkvb, Vt,
      512, 512, 0, 1024, 0, 512);
  // 2. flash attention -> Ob (XCD-swizzled 1D grid, 64 q-rows/wave)
  fa_k<<<512, 256, 0, stream>>>(qkvb, Vt, Ob);
  // 3. h = [x | O] @ [W1_top ; W'] + b1f -> hb bf16 (proj GEMM eliminated)
  gemm_mfma<1, 1, 1><<<dim3(128, 8), 256, 0, stream>>>(
      xb, Ob, W1T, WfT, b1f, nullptr, nullptr, nullptr, hb, nullptr,
      512, 1024, 512, 1024, 512, 1024);
  // 4. LayerNorm + GELU in place
  ln_gelu_k<<<16384, 256, 0, stream>>>(hb, ln_g, ln_b);
  // 5. out = x + g @ W2 + b2 -> fp32 d_out (bf16 resid from xb via Vt slot)
  gemm_mfma<0, 0, 2><<<dim3(128, 4), 256, 0, stream>>>(
      hb, nullptr, W2T, nullptr, b2, nullptr, nullptr, (float*)d_out, nullptr, xb,
      1024, 1024, 0, 512, 0, 1024);
}